// Round 13
// baseline (84.339 us; speedup 1.0000x reference)
//
#include <hip/hip_runtime.h>
#include <hip/hip_bf16.h>

// Problem constants (fixed by the bench): B=2, Tq=Tv=2048, D=512, H=8, dh=64.
// Inputs and output are FLOAT32.
#define BATCH 2
#define TSEQ  2048
#define DMODEL 512
#define NHEAD 8
#define DHEAD 64

typedef __bf16 bf16x2 __attribute__((ext_vector_type(2)));
typedef __bf16 bf16x4 __attribute__((ext_vector_type(4)));
typedef __bf16 bf16x8 __attribute__((ext_vector_type(8)));
typedef float  f32x4  __attribute__((ext_vector_type(4)));

__device__ __forceinline__ bf16x8 load_b8(const void* p) {
  return __builtin_bit_cast(bf16x8, *reinterpret_cast<const uint4*>(p));
}

// load 8 fp32 and convert to bf16x8 (p must be 16B-aligned)
__device__ __forceinline__ bf16x8 cvt8(const float* p) {
  float4 a = *reinterpret_cast<const float4*>(p);
  float4 b = *reinterpret_cast<const float4*>(p + 4);
  bf16x8 r;
  r[0] = (__bf16)a.x; r[1] = (__bf16)a.y; r[2] = (__bf16)a.z; r[3] = (__bf16)a.w;
  r[4] = (__bf16)b.x; r[5] = (__bf16)b.y; r[6] = (__bf16)b.z; r[7] = (__bf16)b.w;
  return r;
}

// load 8 fp32, scale, convert to bf16x8
__device__ __forceinline__ bf16x8 cvt8s(const float* p, float s) {
  float4 a = *reinterpret_cast<const float4*>(p);
  float4 b = *reinterpret_cast<const float4*>(p + 4);
  bf16x8 r;
  r[0] = (__bf16)(a.x * s); r[1] = (__bf16)(a.y * s);
  r[2] = (__bf16)(a.z * s); r[3] = (__bf16)(a.w * s);
  r[4] = (__bf16)(b.x * s); r[5] = (__bf16)(b.y * s);
  r[6] = (__bf16)(b.z * s); r[7] = (__bf16)(b.w * s);
  return r;
}

// pack two f32 to bf16 pair by truncation (elem0=a's hi16, elem1=b's hi16)
__device__ __forceinline__ uint packbf(float a, float b) {
  uint ua = __builtin_bit_cast(uint, a);
  uint ub = __builtin_bit_cast(uint, b);
  return (ua >> 16) | (ub & 0xFFFF0000u);
}

// Tiled K layout: Kt[b][tset(128)][h(8)][g(2)][lane(64)][8elem]  (4 MiB)
#define KT_B   1048576   // elems per batch = 128*8192
#define KT_T   8192      // elems per tset
// Tiled V layout: Vtile[b][kset32(64)][dt(4)][lane(64)][8elem]   (512 KiB)
#define VT_B   131072    // elems per batch = 64*2048
#define VT_K   2048      // elems per kset32

// ---------------------------------------------------------------------------
// Kernel 1: conv1d(k=1): Kt[...] = bf16( V @ W^T + bias ) in tiled layout.
// ---------------------------------------------------------------------------
__global__ __launch_bounds__(256) void conv_kernel(
    const float* __restrict__ V,
    const float* __restrict__ W,
    const float* __restrict__ bias,
    __hip_bfloat16* __restrict__ Kt) {
  const int bx = blockIdx.x;
  const int b    = bx >> 7;
  const int tset = bx & 127;
  const int t0   = tset << 4;
  const int w  = threadIdx.x >> 6;
  const int l  = threadIdx.x & 63;
  const int lm = l & 15;
  const int lg = l >> 4;

  const float* vrow = V + ((size_t)(b * TSEQ + t0 + lm)) * DHEAD;
  bf16x8 av0 = cvt8(vrow + lg * 8);
  bf16x8 av1 = cvt8(vrow + 32 + lg * 8);

  #pragma unroll
  for (int n = 0; n < 8; ++n) {
    const int o0 = (w * 8 + n) * 16;
    const float* wrow = W + ((size_t)(o0 + lm)) * DHEAD;
    bf16x8 b0 = cvt8(wrow + lg * 8);
    bf16x8 b1 = cvt8(wrow + 32 + lg * 8);
    f32x4 acc = {0.f, 0.f, 0.f, 0.f};
    acc = __builtin_amdgcn_mfma_f32_16x16x32_bf16(av0, b0, acc, 0, 0, 0);
    acc = __builtin_amdgcn_mfma_f32_16x16x32_bf16(av1, b1, acc, 0, 0, 0);
    const int o   = o0 + lm;
    const int h   = o >> 6;
    const int gg  = (o >> 5) & 1;
    const int lgt = (o >> 3) & 3;
    const int j   = o & 7;
    const float bv = bias[o];
    const size_t kbase = (size_t)b * KT_B + (size_t)tset * KT_T +
                         h * 1024 + gg * 512 + lgt * 128 + j;
    #pragma unroll
    for (int r = 0; r < 4; ++r)
      Kt[kbase + (size_t)(lg * 4 + r) * 8] = __float2bfloat16(acc[r] + bv);
  }
}

// ---------------------------------------------------------------------------
// Kernel 2: Vtile from V via LDS tile transpose.
// ---------------------------------------------------------------------------
__global__ __launch_bounds__(256) void vt_kernel(const float* __restrict__ V,
                                                 __hip_bfloat16* __restrict__ Vtile) {
  const int bx = blockIdx.x;
  const int b  = bx >> 5;
  const int t0 = (bx & 31) << 6;
  const int tid = threadIdx.x;
  __shared__ float tile[64][65];

  #pragma unroll
  for (int p = 0; p < 4; ++p) {
    const int r = p * 16 + (tid >> 4);
    const int c = (tid & 15) * 4;
    float4 v = *reinterpret_cast<const float4*>(
        &V[((size_t)(b * TSEQ + t0 + r)) * DHEAD + c]);
    tile[r][c]     = v.x;
    tile[r][c + 1] = v.y;
    tile[r][c + 2] = v.z;
    tile[r][c + 3] = v.w;
  }
  __syncthreads();

  const int dt = tid >> 6;            // 0..3
  const int l  = tid & 63;
  const int lm = l & 15;
  const int lg = l >> 4;
  #pragma unroll
  for (int ks2 = 0; ks2 < 2; ++ks2) {
    bf16x8 o;
    #pragma unroll
    for (int jj = 0; jj < 4; ++jj) {
      o[jj]     = (__bf16)tile[ks2 * 32 + lg * 4 + jj][dt * 16 + lm];
      o[jj + 4] = (__bf16)tile[ks2 * 32 + 16 + lg * 4 + jj][dt * 16 + lm];
    }
    *reinterpret_cast<uint4*>(
        Vtile + (size_t)b * VT_B + (size_t)((t0 >> 5) + ks2) * VT_K +
        dt * 512 + l * 8) = __builtin_bit_cast(uint4, o);
  }
}

// ---------------------------------------------------------------------------
// Kernel 3: fused attention, softmax over HEADS (lane-local), barrier-free
// pipelined k-loop (256 threads, 4 waves, ~244 VGPR, no spill).
// R13: deepen k-split 2->4 (KCH=4: 1024 blocks, NPR=4). R12's occupancy
// counter (10.5% vs 25% ceiling) showed the 2nd block/CU is absent ~60% of
// the runtime (ramp+tail at coarse chunks); quartering per-block work keeps
// the CU queue fed. Partials stored bf16 (RNE) so 4 chunks fit the same
// 16 MB ws budget that the 2-way fp32 split used.
// ---------------------------------------------------------------------------
template <int KCH>   // 1 = no split (fp32 direct out), 4 = quad split
__global__ __launch_bounds__(256, 1) void attn_kernel(
    const float* __restrict__ Q,
    const __hip_bfloat16* __restrict__ Kt,
    const __hip_bfloat16* __restrict__ Vtile,
    float* __restrict__ Out,
    __hip_bfloat16* __restrict__ Pp) {
  const int bx = blockIdx.x;
  int b, q0, c;
  if (KCH == 4) {     // 1024 blocks: XCD x gets logical [x*128, x*128+128)
    const int L = (bx & 7) * 128 + (bx >> 3);
    b = L >> 9; const int rest = L & 511; q0 = (rest >> 2) << 4; c = rest & 3;
  } else {            // 256 blocks
    const int L = (bx & 7) * 32 + (bx >> 3);
    b = L >> 7; q0 = (L & 127) << 4; c = 0;
  }
  const int tid = threadIdx.x;
  const int w  = tid >> 6;            // 0..3
  const int l  = tid & 63;
  const int lm = l & 15;
  const int lg = l >> 4;

  constexpr int NPR = 16 / KCH;                  // 32-k iterations per wave
  const int kt16 = c * (128 / KCH) + w * (32 / KCH);   // tset base
  const int kv32 = kt16 >> 1;                          // kset32 base

  __shared__ float Obuf[4][64][17];   // [wave][d][q+pad] reduction buffer

  // ---- Q fragments in registers, PRE-SCALED by dh^-0.5 * log2(e) ----
  const float cl2 = 0.125f * 1.44269504f;
  bf16x8 qf[NHEAD][2];
  {
    const float* qrow = Q + ((size_t)(b * TSEQ + q0 + lm)) * DMODEL + lg * 8;
    #pragma unroll
    for (int h = 0; h < NHEAD; ++h) {
      qf[h][0] = cvt8s(qrow + h * DHEAD, cl2);
      qf[h][1] = cvt8s(qrow + h * DHEAD + 32, cl2);
    }
  }

  f32x4 accO[NHEAD][4];   // [h][dt], O^T: d = dt*16 + lg*4 + r, q = lm
  #pragma unroll
  for (int h = 0; h < NHEAD; ++h)
    #pragma unroll
    for (int j = 0; j < 4; ++j) accO[h][j] = (f32x4){0.f, 0.f, 0.f, 0.f};

  // Pipeline buffers (all statically named/indexed).
  bf16x8 kbA[NHEAD][2], kbB[NHEAD][2];       // K half-tile double buffer
  bf16x8 vA[4], vB[4];                       // V iteration double buffer

  #define LOAD_KHALF(buf, tset)                                               \
    {                                                                         \
      const __hip_bfloat16* kb_ =                                             \
          Kt + (size_t)b * KT_B + (size_t)(tset) * KT_T + l * 8;              \
      _Pragma("unroll")                                                       \
      for (int h = 0; h < NHEAD; ++h) {                                       \
        buf[h][0] = load_b8(kb_ + h * 1024);                                  \
        buf[h][1] = load_b8(kb_ + h * 1024 + 512);                            \
      }                                                                       \
    }

  #define LOAD_V(vbuf, k32)                                                   \
    {                                                                         \
      const __hip_bfloat16* vb_ =                                             \
          Vtile + (size_t)b * VT_B + (size_t)(k32) * VT_K + l * 8;            \
      _Pragma("unroll")                                                       \
      for (int dt = 0; dt < 4; ++dt) vbuf[dt] = load_b8(vb_ + dt * 512);      \
    }

  // S half: MFMA (pre-scaled Q), no-max softmax over heads, truncation pack.
  #define S_HALF(kbuf, s2)                                                    \
    {                                                                         \
      f32x4 sv[NHEAD];                                                        \
      __builtin_amdgcn_s_setprio(1);                                          \
      _Pragma("unroll")                                                       \
      for (int h = 0; h < NHEAD; ++h) {                                       \
        f32x4 t = {0.f, 0.f, 0.f, 0.f};                                       \
        t = __builtin_amdgcn_mfma_f32_16x16x32_bf16(kbuf[h][0], qf[h][0], t, 0, 0, 0); \
        t = __builtin_amdgcn_mfma_f32_16x16x32_bf16(kbuf[h][1], qf[h][1], t, 0, 0, 0); \
        sv[h] = t;                                                            \
      }                                                                       \
      __builtin_amdgcn_s_setprio(0);                                          \
      _Pragma("unroll")                                                       \
      for (int rp = 0; rp < 2; ++rp) {                                        \
        float w0_[NHEAD], w1_[NHEAD];                                         \
        float s0_ = 0.f, s1_ = 0.f;                                           \
        _Pragma("unroll")                                                     \
        for (int h = 0; h < NHEAD; ++h) { w0_[h] = exp2f(sv[h][2 * rp]);     s0_ += w0_[h]; } \
        _Pragma("unroll")                                                     \
        for (int h = 0; h < NHEAD; ++h) { w1_[h] = exp2f(sv[h][2 * rp + 1]); s1_ += w1_[h]; } \
        const float i0_ = __builtin_amdgcn_rcpf(s0_);                         \
        const float i1_ = __builtin_amdgcn_rcpf(s1_);                         \
        _Pragma("unroll")                                                     \
        for (int h = 0; h < NHEAD; ++h)                                       \
          wfu[h][(s2) * 2 + rp] = packbf(w0_[h] * i0_, w1_[h] * i1_);         \
      }                                                                       \
    }

  #define PRBODY(PR, VA, VB)                                                  \
    {                                                                         \
      const int PN = (PR) < NPR - 1 ? (PR) + 1 : NPR - 1;                     \
      uint wfu[NHEAD][4];                                                     \
      LOAD_KHALF(kbB, kt16 + 2 * (PR) + 1);  /* issue: this pr, s2=1 */       \
      S_HALF(kbA, 0);                        /* consume kbA */                \
      LOAD_KHALF(kbA, kt16 + 2 * PN);        /* issue: next pr, s2=0 */       \
      S_HALF(kbB, 1);                        /* consume kbB */                \
      LOAD_V(VB, kv32 + PN);                 /* issue: next pr V */           \
      __builtin_amdgcn_s_setprio(1);                                          \
      _Pragma("unroll")                                                       \
      for (int h = 0; h < NHEAD; ++h) {      /* consume VA (direct A-frag) */ \
        const bf16x8 wfv = __builtin_bit_cast(bf16x8,                         \
            uint4{wfu[h][0], wfu[h][1], wfu[h][2], wfu[h][3]});               \
        _Pragma("unroll")                                                     \
        for (int dt = 0; dt < 4; ++dt)                                        \
          accO[h][dt] = __builtin_amdgcn_mfma_f32_16x16x32_bf16(VA[dt], wfv, accO[h][dt], 0, 0, 0); \
      }                                                                       \
      __builtin_amdgcn_s_setprio(0);                                          \
    }

  // prologue: fill kbA and vA for pr=0
  LOAD_KHALF(kbA, kt16);
  LOAD_V(vA, kv32);

  #pragma unroll 1
  for (int prp = 0; prp < NPR / 2; ++prp) {
    PRBODY(2 * prp,     vA, vB);
    PRBODY(2 * prp + 1, vB, vA);
  }

  #undef PRBODY
  #undef S_HALF
  #undef LOAD_V
  #undef LOAD_KHALF

  // ---- epilogue: reduce 4 k-strip waves via LDS, one head per round.
  //      FULLY UNROLLED so accO indexing stays compile-time.
  __hip_bfloat16* pbase = Pp +
      ((size_t)((b * 128 + (q0 >> 4)) * 4 + c)) * 8192;
  float* obase = Out + ((size_t)(b * TSEQ + q0)) * DMODEL;
  #pragma unroll
  for (int h = 0; h < NHEAD; ++h) {
    #pragma unroll
    for (int dt = 0; dt < 4; ++dt)
      #pragma unroll
      for (int r = 0; r < 4; ++r)
        Obuf[w][dt * 16 + lg * 4 + r][lm] = accO[h][dt][r];
    __syncthreads();

    {
      const int q  = tid >> 4;         // 0..15
      const int d0 = (tid & 15) * 4;   // 4 d per thread
      float4 s = {0.f, 0.f, 0.f, 0.f};
      #pragma unroll
      for (int ww = 0; ww < 4; ++ww) {
        s.x += Obuf[ww][d0][q];
        s.y += Obuf[ww][d0 + 1][q];
        s.z += Obuf[ww][d0 + 2][q];
        s.w += Obuf[ww][d0 + 3][q];
      }
      if (KCH == 4) {
        bf16x4 pb;
        pb[0] = (__bf16)s.x; pb[1] = (__bf16)s.y;
        pb[2] = (__bf16)s.z; pb[3] = (__bf16)s.w;
        *reinterpret_cast<uint2*>(&pbase[(size_t)q * 512 + h * DHEAD + d0]) =
            __builtin_bit_cast(uint2, pb);
      } else {
        *reinterpret_cast<float4*>(&obase[(size_t)q * 512 + h * DHEAD + d0]) = s;
      }
    }
    __syncthreads();
  }
}

// ---------------------------------------------------------------------------
// Kernel 4 (split mode): Out = sum of 4 bf16 partial chunks.
// 1024 blocks x 256 threads; each thread produces 8 contiguous outputs.
// ---------------------------------------------------------------------------
__global__ void reduce_kernel(const __hip_bfloat16* __restrict__ Pp,
                              float* __restrict__ Out) {
  const int g  = blockIdx.x * 256 + threadIdx.x;   // 0..262143
  const int f0 = g << 3;
  const int d0 = f0 & 511;
  const int q  = (f0 >> 9) & 2047;
  const int b  = f0 >> 20;
  const __hip_bfloat16* p = Pp +
      ((size_t)(b * 128 + (q >> 4)) * 4) * 8192 + (size_t)(q & 15) * 512 + d0;
  float acc[8] = {0.f, 0.f, 0.f, 0.f, 0.f, 0.f, 0.f, 0.f};
  #pragma unroll
  for (int c = 0; c < 4; ++c) {
    uint4 u = *reinterpret_cast<const uint4*>(p + c * 8192);
    const uint uu[4] = {u.x, u.y, u.z, u.w};
    #pragma unroll
    for (int j = 0; j < 4; ++j) {
      acc[2 * j]     += __builtin_bit_cast(float, uu[j] << 16);
      acc[2 * j + 1] += __builtin_bit_cast(float, uu[j] & 0xFFFF0000u);
    }
  }
  float4* o = reinterpret_cast<float4*>(Out + f0);
  o[0] = float4{acc[0], acc[1], acc[2], acc[3]};
  o[1] = float4{acc[4], acc[5], acc[6], acc[7]};
}

// ---------------------------------------------------------------------------
extern "C" void kernel_launch(void* const* d_in, const int* in_sizes, int n_in,
                              void* d_out, int out_size, void* d_ws, size_t ws_size,
                              hipStream_t stream) {
  const float* Q    = (const float*)d_in[0];
  const float* V    = (const float*)d_in[1];
  const float* W    = (const float*)d_in[2];
  const float* bias = (const float*)d_in[3];
  float* Out = (float*)d_out;

  // ws layout: Kt bf16 4MiB | Vtile bf16 512KiB | P bf16 16MiB (split only)
  __hip_bfloat16* Ktb = (__hip_bfloat16*)d_ws;
  __hip_bfloat16* Vtb = Ktb + (size_t)BATCH * KT_B;
  const size_t pOff = 4u * 1024 * 1024 + 512u * 1024;
  __hip_bfloat16* Pp = (__hip_bfloat16*)((char*)d_ws + pOff);
  const bool split = ws_size >= pOff + (size_t)4 * BATCH * TSEQ * DMODEL * 2;

  conv_kernel<<<256, 256, 0, stream>>>(V, W, bias, Ktb);
  vt_kernel<<<64, 256, 0, stream>>>(V, Vtb);
  if (split) {
    attn_kernel<4><<<1024, 256, 0, stream>>>(Q, Ktb, Vtb, Out, Pp);
    reduce_kernel<<<1024, 256, 0, stream>>>(Pp, Out);
  } else {
    attn_kernel<1><<<256, 256, 0, stream>>>(Q, Ktb, Vtb, Out, Pp);
  }
}

// Round 14
// 53.878 us; speedup vs baseline: 1.5654x; 1.5654x over previous
//
#include <hip/hip_runtime.h>
#include <hip/hip_bf16.h>

// Problem constants (fixed by the bench): B=2, Tq=Tv=2048, D=512, H=8, dh=64.
// Inputs and output are FLOAT32.
#define BATCH 2
#define TSEQ  2048
#define DMODEL 512
#define NHEAD 8
#define DHEAD 64

typedef __bf16 bf16x2 __attribute__((ext_vector_type(2)));
typedef __bf16 bf16x4 __attribute__((ext_vector_type(4)));
typedef __bf16 bf16x8 __attribute__((ext_vector_type(8)));
typedef float  f32x4  __attribute__((ext_vector_type(4)));

#if __has_builtin(__builtin_amdgcn_exp2f)
#define EXP2(x) __builtin_amdgcn_exp2f(x)   // raw v_exp_f32 (exp2f links ocml)
#else
#define EXP2(x) exp2f(x)
#endif

__device__ __forceinline__ bf16x8 load_b8(const void* p) {
  return __builtin_bit_cast(bf16x8, *reinterpret_cast<const uint4*>(p));
}

// load 8 fp32 and convert to bf16x8 (p must be 16B-aligned)
__device__ __forceinline__ bf16x8 cvt8(const float* p) {
  float4 a = *reinterpret_cast<const float4*>(p);
  float4 b = *reinterpret_cast<const float4*>(p + 4);
  bf16x8 r;
  r[0] = (__bf16)a.x; r[1] = (__bf16)a.y; r[2] = (__bf16)a.z; r[3] = (__bf16)a.w;
  r[4] = (__bf16)b.x; r[5] = (__bf16)b.y; r[6] = (__bf16)b.z; r[7] = (__bf16)b.w;
  return r;
}

// load 8 fp32, scale, convert to bf16x8
__device__ __forceinline__ bf16x8 cvt8s(const float* p, float s) {
  float4 a = *reinterpret_cast<const float4*>(p);
  float4 b = *reinterpret_cast<const float4*>(p + 4);
  bf16x8 r;
  r[0] = (__bf16)(a.x * s); r[1] = (__bf16)(a.y * s);
  r[2] = (__bf16)(a.z * s); r[3] = (__bf16)(a.w * s);
  r[4] = (__bf16)(b.x * s); r[5] = (__bf16)(b.y * s);
  r[6] = (__bf16)(b.z * s); r[7] = (__bf16)(b.w * s);
  return r;
}

// pack two f32 to bf16 pair by truncation
__device__ __forceinline__ uint packbf(float a, float b) {
  uint ua = __builtin_bit_cast(uint, a);
  uint ub = __builtin_bit_cast(uint, b);
  return (ua >> 16) | (ub & 0xFFFF0000u);
}

// Tiled K layout: Kt[b][tset(128)][h(8)][g(2)][lane(64)][8elem]  (4 MiB)
#define KT_B   1048576
#define KT_T   8192
// Tiled V layout: Vtile[b][kset32(64)][dt(4)][lane(64)][8elem]   (512 KiB)
#define VT_B   131072
#define VT_K   2048

// ---------------------------------------------------------------------------
// Kernel 1: conv1d(k=1): Kt = bf16( V @ W^T + bias ) in tiled layout.
// ---------------------------------------------------------------------------
__global__ __launch_bounds__(256) void conv_kernel(
    const float* __restrict__ V,
    const float* __restrict__ W,
    const float* __restrict__ bias,
    __hip_bfloat16* __restrict__ Kt) {
  const int bx = blockIdx.x;
  const int b    = bx >> 7;
  const int tset = bx & 127;
  const int t0   = tset << 4;
  const int w  = threadIdx.x >> 6;
  const int l  = threadIdx.x & 63;
  const int lm = l & 15;
  const int lg = l >> 4;

  const float* vrow = V + ((size_t)(b * TSEQ + t0 + lm)) * DHEAD;
  bf16x8 av0 = cvt8(vrow + lg * 8);
  bf16x8 av1 = cvt8(vrow + 32 + lg * 8);

  #pragma unroll
  for (int n = 0; n < 8; ++n) {
    const int o0 = (w * 8 + n) * 16;
    const float* wrow = W + ((size_t)(o0 + lm)) * DHEAD;
    bf16x8 b0 = cvt8(wrow + lg * 8);
    bf16x8 b1 = cvt8(wrow + 32 + lg * 8);
    f32x4 acc = {0.f, 0.f, 0.f, 0.f};
    acc = __builtin_amdgcn_mfma_f32_16x16x32_bf16(av0, b0, acc, 0, 0, 0);
    acc = __builtin_amdgcn_mfma_f32_16x16x32_bf16(av1, b1, acc, 0, 0, 0);
    const int o   = o0 + lm;
    const int h   = o >> 6;
    const int gg  = (o >> 5) & 1;
    const int lgt = (o >> 3) & 3;
    const int j   = o & 7;
    const float bv = bias[o];
    const size_t kbase = (size_t)b * KT_B + (size_t)tset * KT_T +
                         h * 1024 + gg * 512 + lgt * 128 + j;
    #pragma unroll
    for (int r = 0; r < 4; ++r)
      Kt[kbase + (size_t)(lg * 4 + r) * 8] = __float2bfloat16(acc[r] + bv);
  }
}

// ---------------------------------------------------------------------------
// Kernel 2: Vtile from V via LDS tile transpose.
// ---------------------------------------------------------------------------
__global__ __launch_bounds__(256) void vt_kernel(const float* __restrict__ V,
                                                 __hip_bfloat16* __restrict__ Vtile) {
  const int bx = blockIdx.x;
  const int b  = bx >> 5;
  const int t0 = (bx & 31) << 6;
  const int tid = threadIdx.x;
  __shared__ float tile[64][65];

  #pragma unroll
  for (int p = 0; p < 4; ++p) {
    const int r = p * 16 + (tid >> 4);
    const int c = (tid & 15) * 4;
    float4 v = *reinterpret_cast<const float4*>(
        &V[((size_t)(b * TSEQ + t0 + r)) * DHEAD + c]);
    tile[r][c]     = v.x;
    tile[r][c + 1] = v.y;
    tile[r][c + 2] = v.z;
    tile[r][c + 3] = v.w;
  }
  __syncthreads();

  const int dt = tid >> 6;
  const int l  = tid & 63;
  const int lm = l & 15;
  const int lg = l >> 4;
  #pragma unroll
  for (int ks2 = 0; ks2 < 2; ++ks2) {
    bf16x8 o;
    #pragma unroll
    for (int jj = 0; jj < 4; ++jj) {
      o[jj]     = (__bf16)tile[ks2 * 32 + lg * 4 + jj][dt * 16 + lm];
      o[jj + 4] = (__bf16)tile[ks2 * 32 + 16 + lg * 4 + jj][dt * 16 + lm];
    }
    *reinterpret_cast<uint4*>(
        Vtile + (size_t)b * VT_B + (size_t)((t0 >> 5) + ks2) * VT_K +
        dt * 512 + l * 8) = __builtin_bit_cast(uint4, o);
  }
}

// ---------------------------------------------------------------------------
// Kernel 3 (R14): low-register cooperative attention.
// 256 threads = 4 waves; per 128-k round: S-phase wave w does its 32-k strip
// (all heads, softmax lane-local) -> W to LDS in B-frag layout; PV-phase
// wave w owns d-quadrant dt=w for ALL heads, reading all strips' W from LDS.
// accO shrinks 128->32 regs; Q lives in LDS (XOR-swizzled). Total regs
// ~230 incl AGPR -> 2 waves/SIMD co-residency (the R13 lesson: VGPR_Count
// excludes AGPRs; old structure was ~380 total = locked at 1 wave/SIMD).
// KCH=2: 512 blocks = exactly 2 resident blocks/CU, no tail.
// ---------------------------------------------------------------------------
template <int KCH>   // 1 = no split (direct fp32 out), 2 = half split
__global__ __launch_bounds__(256, 2) void attn_kernel(
    const float* __restrict__ Q,
    const __hip_bfloat16* __restrict__ Kt,
    const __hip_bfloat16* __restrict__ Vtile,
    float* __restrict__ Out,
    float* __restrict__ P) {
  const int bx = blockIdx.x;
  int b, q0, c;
  if (KCH == 2) {     // 512 blocks: XCD x gets logical [x*64, x*64+64)
    const int L = (bx & 7) * 64 + (bx >> 3);
    b = L >> 8; const int rest = L & 255; q0 = (rest >> 1) << 4; c = rest & 1;
  } else {            // 256 blocks
    const int L = (bx & 7) * 32 + (bx >> 3);
    b = L >> 7; q0 = (L & 127) << 4; c = 0;
  }
  const int tid = threadIdx.x;
  const int w  = tid >> 6;            // 0..3
  const int l  = tid & 63;
  const int lm = l & 15;
  const int lg = l >> 4;

  constexpr int NRND = KCH == 2 ? 8 : 16;   // 128-k rounds
  const int tsbase = c * 64;                // tset base (16-k units)
  const int kvbase = c * 32;                // kset32 base

  __shared__ __bf16 Qs[16 * 512];           // 16 KiB, XOR-swizzled
  __shared__ __bf16 Ws[4][NHEAD][512];      // 32 KiB, B-frag layout
  __shared__ float  Obuf[64][17];           // 4.4 KiB epilogue transpose

  // ---- stage Q tile to LDS (bf16, pre-scaled by dh^-0.5*log2e, swizzled) --
  const float cl2 = 0.125f * 1.44269504f;
  {
    const int row = tid >> 4;          // 0..15
    const int seg = tid & 15;          // 32 floats each
    const float* src = Q + ((size_t)(b * TSEQ + q0 + row)) * DMODEL + seg * 32;
    char* base = (char*)Qs;
    const int sw = (row & 7) << 4;
    #pragma unroll
    for (int u = 0; u < 4; ++u) {
      bf16x8 v = cvt8s(src + u * 8, cl2);
      *(bf16x8*)(base + ((row * 1024 + seg * 64 + u * 16) ^ sw)) = v;
    }
  }
  __syncthreads();

  f32x4 accO[NHEAD];    // [h]: q = lm, d = w*16 + lg*4 + r  (32 regs)
  #pragma unroll
  for (int h = 0; h < NHEAD; ++h) accO[h] = (f32x4){0.f, 0.f, 0.f, 0.f};

  const char* qb = (const char*)Qs;
  const int qsw = (lm & 7) << 4;

  bf16x8 vA[4], vB[4];                 // V per-round double buffer (dt=w)

  #define S_HALF(TSET, S2)                                                    \
    {                                                                         \
      const __hip_bfloat16* kb_ =                                             \
          Kt + (size_t)b * KT_B + (size_t)(TSET) * KT_T + l * 8;              \
      bf16x8 kf0[NHEAD], kf1[NHEAD];                                          \
      _Pragma("unroll")                                                       \
      for (int h = 0; h < NHEAD; ++h) {                                       \
        kf0[h] = load_b8(kb_ + h * 1024);                                     \
        kf1[h] = load_b8(kb_ + h * 1024 + 512);                               \
      }                                                                       \
      f32x4 sv[NHEAD];                                                        \
      __builtin_amdgcn_s_setprio(1);                                          \
      _Pragma("unroll")                                                       \
      for (int h = 0; h < NHEAD; ++h) {                                       \
        bf16x8 q0_ = *(const bf16x8*)(qb + ((lm * 1024 + h * 128 + lg * 16) ^ qsw)); \
        bf16x8 q1_ = *(const bf16x8*)(qb + ((lm * 1024 + h * 128 + 64 + lg * 16) ^ qsw)); \
        f32x4 t = {0.f, 0.f, 0.f, 0.f};                                       \
        t = __builtin_amdgcn_mfma_f32_16x16x32_bf16(kf0[h], q0_, t, 0, 0, 0); \
        t = __builtin_amdgcn_mfma_f32_16x16x32_bf16(kf1[h], q1_, t, 0, 0, 0); \
        sv[h] = t;                                                            \
      }                                                                       \
      __builtin_amdgcn_s_setprio(0);                                          \
      _Pragma("unroll")                                                       \
      for (int rp = 0; rp < 2; ++rp) {                                        \
        float w0_[NHEAD], w1_[NHEAD];                                         \
        float s0_ = 0.f, s1_ = 0.f;                                           \
        _Pragma("unroll")                                                     \
        for (int h = 0; h < NHEAD; ++h) { w0_[h] = EXP2(sv[h][2 * rp]);     s0_ += w0_[h]; } \
        _Pragma("unroll")                                                     \
        for (int h = 0; h < NHEAD; ++h) { w1_[h] = EXP2(sv[h][2 * rp + 1]); s1_ += w1_[h]; } \
        const float i0_ = __builtin_amdgcn_rcpf(s0_);                         \
        const float i1_ = __builtin_amdgcn_rcpf(s1_);                         \
        _Pragma("unroll")                                                     \
        for (int h = 0; h < NHEAD; ++h)                                       \
          wfu[h][(S2) * 2 + rp] = packbf(w0_[h] * i0_, w1_[h] * i1_);         \
      }                                                                       \
    }

  #define ROUND(R, VCUR, VNXT)                                                \
    {                                                                         \
      uint wfu[NHEAD][4];                                                     \
      const int ts0 = tsbase + (R) * 8 + w * 2;                               \
      S_HALF(ts0, 0);                                                         \
      S_HALF(ts0 + 1, 1);                                                     \
      _Pragma("unroll")                                                       \
      for (int h = 0; h < NHEAD; ++h)                                         \
        *reinterpret_cast<uint4*>((char*)(&Ws[w][h][0]) + l * 16) =           \
            uint4{wfu[h][0], wfu[h][1], wfu[h][2], wfu[h][3]};                \
      {                                                                       \
        const int RN = (R) < NRND - 1 ? (R) + 1 : NRND - 1;                   \
        const __hip_bfloat16* vb_ = Vtile + (size_t)b * VT_B +                \
            (size_t)(kvbase + RN * 4) * VT_K + w * 512 + l * 8;               \
        _Pragma("unroll")                                                     \
        for (int s = 0; s < 4; ++s) VNXT[s] = load_b8(vb_ + s * 2048);        \
      }                                                                       \
      __syncthreads();                                                        \
      __builtin_amdgcn_s_setprio(1);                                          \
      _Pragma("unroll")                                                       \
      for (int s = 0; s < 4; ++s) {                                           \
        _Pragma("unroll")                                                     \
        for (int h = 0; h < NHEAD; ++h) {                                     \
          bf16x8 wsf = *(const bf16x8*)((const char*)(&Ws[s][h][0]) + l * 16);\
          accO[h] = __builtin_amdgcn_mfma_f32_16x16x32_bf16(VCUR[s], wsf, accO[h], 0, 0, 0); \
        }                                                                     \
      }                                                                       \
      __builtin_amdgcn_s_setprio(0);                                          \
      __syncthreads();                                                        \
    }

  // prologue: V for round 0
  {
    const __hip_bfloat16* vb_ = Vtile + (size_t)b * VT_B +
        (size_t)kvbase * VT_K + w * 512 + l * 8;
    #pragma unroll
    for (int s = 0; s < 4; ++s) vA[s] = load_b8(vb_ + s * 2048);
  }

  #pragma unroll 1
  for (int rp2 = 0; rp2 < NRND / 2; ++rp2) {
    ROUND(2 * rp2,     vA, vB);
    ROUND(2 * rp2 + 1, vB, vA);
  }

  #undef ROUND
  #undef S_HALF

  // ---- epilogue: per head, LDS transpose then coalesced store ----
  float* outbase = (KCH == 2)
      ? P + ((size_t)((b * 128 + (q0 >> 4)) * 2 + c)) * 8192
      : Out + ((size_t)(b * TSEQ + q0)) * DMODEL;
  #pragma unroll
  for (int h = 0; h < NHEAD; ++h) {
    #pragma unroll
    for (int r = 0; r < 4; ++r)
      Obuf[w * 16 + lg * 4 + r][lm] = accO[h][r];
    __syncthreads();
    {
      const int q  = tid >> 4;         // 0..15
      const int d0 = (tid & 15) * 4;   // within-head d, 0..60
      float4 s = {Obuf[d0][q], Obuf[d0 + 1][q], Obuf[d0 + 2][q], Obuf[d0 + 3][q]};
      *reinterpret_cast<float4*>(&outbase[(size_t)q * 512 + h * DHEAD + d0]) = s;
    }
    __syncthreads();
  }
}

// ---------------------------------------------------------------------------
// Kernel 4 (split mode): Out = P[half0] + P[half1].
// ---------------------------------------------------------------------------
__global__ void reduce_kernel(const float4* __restrict__ P,
                              float4* __restrict__ Out) {
  const int g = blockIdx.x * 256 + threadIdx.x;   // 0..524287
  const int f = g << 2;
  const int d = f & 511;
  const int q = (f >> 9) & 2047;
  const int b = f >> 20;
  const size_t p0 = (((size_t)(b * 128 + (q >> 4)) * 2) * 8192 +
                     (size_t)(q & 15) * 512 + d) >> 2;
  float4 a = P[p0];
  float4 c = P[p0 + 2048];
  Out[g] = float4{a.x + c.x, a.y + c.y, a.z + c.z, a.w + c.w};
}

// ---------------------------------------------------------------------------
extern "C" void kernel_launch(void* const* d_in, const int* in_sizes, int n_in,
                              void* d_out, int out_size, void* d_ws, size_t ws_size,
                              hipStream_t stream) {
  const float* Q    = (const float*)d_in[0];
  const float* V    = (const float*)d_in[1];
  const float* W    = (const float*)d_in[2];
  const float* bias = (const float*)d_in[3];
  float* Out = (float*)d_out;

  // ws layout: Kt bf16 4MiB | Vtile bf16 512KiB | P fp32 16MiB (split only)
  __hip_bfloat16* Ktb = (__hip_bfloat16*)d_ws;
  __hip_bfloat16* Vtb = Ktb + (size_t)BATCH * KT_B;
  const size_t pOff = 4u * 1024 * 1024 + 512u * 1024;
  float* P = (float*)((char*)d_ws + pOff);
  const bool split = ws_size >= pOff + (size_t)512 * 8192 * 4;

  conv_kernel<<<256, 256, 0, stream>>>(V, W, bias, Ktb);
  vt_kernel<<<64, 256, 0, stream>>>(V, Vtb);
  if (split) {
    attn_kernel<2><<<512, 256, 0, stream>>>(Q, Ktb, Vtb, Out, P);
    reduce_kernel<<<2048, 256, 0, stream>>>((const float4*)P, (float4*)Out);
  } else {
    attn_kernel<1><<<256, 256, 0, stream>>>(Q, Ktb, Vtb, Out, P);
  }
}